// Round 3
// baseline (29235.931 us; speedup 1.0000x reference)
//
#include <hip/hip_runtime.h>

#define TT 800

typedef __attribute__((ext_vector_type(8))) short bf16x8;
typedef __attribute__((ext_vector_type(4))) float f32x4;
typedef unsigned short u16;
typedef unsigned int u32;
typedef unsigned long long u64;

constexpr int TILES = 8, RT = 32, WPT = 17, CW = 16, NWG = TILES * WPT;
constexpr size_t WL0_OFF  = 0;              // [2048][640] bf16
constexpr size_t WL1_OFF  = 2621440;        // [2048][1024] bf16
constexpr size_t WLIN_OFF = 6815744;        // [128][512] bf16
constexpr size_t H0_OFF   = 6946816;        // [2][256][512] bf16
constexpr size_t H1_OFF   = 7471104;        // [2][256][512] bf16
constexpr size_t BAR_OFF  = 7995392;        // 8 tiles * 256B flags
constexpr int HB = 256 * 512;

__device__ __forceinline__ u16 f2b(float x) {
  u32 u = __float_as_uint(x);
  return (u16)((u + 0x7FFFu + ((u >> 16) & 1u)) >> 16);   // RNE fp32->bf16
}
__device__ __forceinline__ float sigf(float x) { return 1.f / (1.f + __expf(-x)); }
__device__ __forceinline__ float tanh_f(float x) { float e = __expf(2.f * x); return 1.f - 2.f / (e + 1.f); }

// Coherent (cross-XCD) ops: sc0 sc1, bypass L1/L2, served at coherence point.
// Weights/z stay plain-cached (L2 warm across all ticks) — no fences anywhere.
__device__ __forceinline__ bf16x8 ld_coh16(const u16* p) {
  union { bf16x8 v; u64 q[2]; } u;
  u.q[0] = __hip_atomic_load((const u64*)p,     __ATOMIC_RELAXED, __HIP_MEMORY_SCOPE_AGENT);
  u.q[1] = __hip_atomic_load((const u64*)p + 1, __ATOMIC_RELAXED, __HIP_MEMORY_SCOPE_AGENT);
  return u.v;
}
__device__ __forceinline__ void st8(u64* p, u64 v) {
  __hip_atomic_store(p, v, __ATOMIC_RELAXED, __HIP_MEMORY_SCOPE_AGENT);
}
__device__ __forceinline__ void fadd(u32* f) {
  __hip_atomic_fetch_add(f, 1u, __ATOMIC_RELAXED, __HIP_MEMORY_SCOPE_AGENT);
}
__device__ __forceinline__ void fpoll(u32* f, u32 thr) {
  while (__hip_atomic_load(f, __ATOMIC_RELAXED, __HIP_MEMORY_SCOPE_AGENT) < thr)
    __builtin_amdgcn_s_sleep(1);
}

__global__ void prep_kernel(const float* __restrict__ wih0, const float* __restrict__ whh0,
                            const float* __restrict__ wih1, const float* __restrict__ whh1,
                            const float* __restrict__ wlinf,
                            u16* __restrict__ wl0, u16* __restrict__ wl1, u16* __restrict__ wlin) {
  int i = blockIdx.x * 256 + threadIdx.x;
  const int N0 = 2048 * 640, N1 = 2048 * 1024, N2 = 128 * 512;
  if (i < N0) {
    int col = i / 640, k = i - col * 640;
    float v = (k < 512) ? whh0[col * 512 + k] : wih0[col * 128 + (k - 512)];
    wl0[i] = f2b(v);
  } else if (i < N0 + N1) {
    int j = i - N0, col = j >> 10, k = j & 1023;
    float v = (k < 512) ? wih1[col * 512 + k] : whh1[col * 512 + (k - 512)];
    wl1[j] = f2b(v);
  } else if (i < N0 + N1 + N2) {
    int j = i - N0 - N1, col = j >> 9, k = j & 511;
    wlin[j] = f2b(wlinf[col * 512 + k]);
  }
}

// 136 persistent WGs: tile = wg/17 (32 rows), w = wg%17.
//   w<16 : compute WG, owns hidden units [w*32, w*32+32) of BOTH layers.
//          Tick tau: L0 computes h0(tau) [stages h0(tau-1) once, reused as
//          L1's input half]; L1 computes h1(tau-1) [stages h1(tau-2)].
//   w==16: logits WG, NLL(tau-2) from staged h1(tau-2).
// Flags (monotonic, per tile): flagA bumped by 16 computes after h0-store;
// flagB bumped by all 17 after h1-store (computes) / h1-stage (logits).
// WAR safety: every consumer STAGES a buffer before bumping the flag the
// next-parity writer gates on, so "flag >= thr" implies all readers done.
__global__ __launch_bounds__(256, 1) void lstm_kernel(
    const float* __restrict__ bih0, const float* __restrict__ bhh0,
    const float* __restrict__ bih1, const float* __restrict__ bhh1,
    const float* __restrict__ blin,
    const int* __restrict__ z, const int* __restrict__ nfr,
    const u16* __restrict__ wl0, const u16* __restrict__ wl1, const u16* __restrict__ wlin,
    u16* __restrict__ h0buf, u16* __restrict__ h1buf,
    u32* __restrict__ bars, float* __restrict__ out) {
  extern __shared__ char smem[];
  u16* h0s = (u16*)smem;            // [32][512] swizzled, 32 KB
  u16* h1s = (u16*)smem + 16384;    // [32][512] swizzled, 32 KB
  const int wg = blockIdx.x, tile = wg / WPT, w = wg - tile * WPT;
  const int tid = threadIdx.x, lane = tid & 63, wv = tid >> 6;
  const int l15 = lane & 15, l4 = lane >> 4;
  const int rb = wv >> 1, sub = wv & 1;
  const int row0 = tile * RT;
  const bool isC = (w < CW);
  u32* fA = bars + tile * 64;
  u32* fB = bars + tile * 64 + 16;
  const f32x4 VZ = {0.f, 0.f, 0.f, 0.f};

  const int r = rb * 16 + l15;      // A-row this lane reads
  const int rx = r & 7;
  const int rbase = r * 512;

  float c0s[4] = {0, 0, 0, 0}, c1s[4] = {0, 0, 0, 0}, accN[4] = {0, 0, 0, 0};
  float bias0[4], bias1[4], biasL[4], nfl[4];
  const u16 *bp0[4], *bp1[4], *bpL[4];
  if (isC) {
#pragma unroll
    for (int g = 0; g < 4; ++g) {
      int col = g * 512 + w * 32 + sub * 16 + l15;
      bias0[g] = bih0[col] + bhh0[col];
      bp0[g] = wl0 + (size_t)col * 640 + l4 * 8;
      bias1[g] = bih1[col] + bhh1[col];
      bp1[g] = wl1 + (size_t)col * 1024 + l4 * 8;
    }
  } else {
#pragma unroll
    for (int cb = 0; cb < 4; ++cb) {
      int col = sub * 64 + cb * 16 + l15;
      biasL[cb] = blin[col];
      bpL[cb] = wlin + (size_t)col * 512 + l4 * 8;
    }
#pragma unroll
    for (int q = 0; q < 4; ++q) nfl[q] = (float)nfr[row0 + rb * 16 + l4 * 4 + q];
  }

  // init: WG0 of each tile zeroes h0 slot1 + h1 slot0/1 tile slices.
  if (w == 0) {
    u64* z0 = (u64*)(h0buf + HB + row0 * 512);
    u64* z1 = (u64*)(h1buf + row0 * 512);
    u64* z2 = (u64*)(h1buf + HB + row0 * 512);
    for (int k = tid; k < 2048; k += 256) { st8(z0 + k, 0); st8(z1 + k, 0); st8(z2 + k, 0); }
  }
  __syncthreads();
  if (tid == 0) { fadd(fA); fadd(fB); fpoll(fA, 17u); }
  __syncthreads();

  // in-wave 16-shfl transpose: (rows-in-q, unit-in-lane) -> 8B row-chunks
  auto tstore = [&](const u16 hb[4], u16* dst) {
    int srcb = (lane >> 4) * 16 + (lane & 3) * 4;
    int qn = (lane >> 2) & 3;
    u32 vo[4] = {0, 0, 0, 0};
#pragma unroll
    for (int q2 = 0; q2 < 4; ++q2) {
      int x = (int)hb[q2];
#pragma unroll
      for (int j = 0; j < 4; ++j) {
        int g = __shfl(x, srcb + j, 64);
        if (qn == q2) vo[j] = (u32)(u16)g;
      }
    }
    u64 pk = (u64)vo[0] | ((u64)vo[1] << 16) | ((u64)vo[2] << 32) | ((u64)vo[3] << 48);
    int Rl = rb * 16 + (lane >> 2);
    int U0 = w * 32 + sub * 16 + (lane & 3) * 4;
    st8((u64*)(dst + Rl * 512 + U0), pk);
  };
  auto ldh0 = [&](int kb) { return *(const bf16x8*)(h0s + rbase + (((kb * 4 + l4) ^ rx) * 8)); };
  auto ldh1 = [&](int kl) { return *(const bf16x8*)(h1s + rbase + (((kl * 4 + l4) ^ rx) * 8)); };

#pragma unroll 1
  for (int tau = 0; tau <= TT + 1; ++tau) {
    // ---- stage h0(tau-1) (compute WGs) ----
    if (isC && tau <= TT) {
      const u16* src = h0buf + ((tau + 1) & 1) * HB + row0 * 512;
#pragma unroll
      for (int it = 0; it < 8; ++it) {
        int i = it * 256 + tid, rr = i >> 6, kc = i & 63;
        *(bf16x8*)(h0s + rr * 512 + ((kc ^ (rr & 7)) * 8)) = ld_coh16(src + rr * 512 + kc * 8);
      }
    }
    __syncthreads();  // s1: h0s ready
    // ---- L0: h0(tau) ----
    if (isC && tau < TT) {
      int zrow = -1;
      if (tau >= 1) zrow = z[(row0 + r) * TT + (tau - 1)];
      bf16x8 bq0[4][4];
#pragma unroll
      for (int p = 0; p < 4; ++p)
#pragma unroll
        for (int g = 0; g < 4; ++g) bq0[p][g] = *(const bf16x8*)(bp0[g] + p * 32);
      f32x4 acc0[4] = {VZ, VZ, VZ, VZ};
      bf16x8 afc = ldh0(0), afn;
#pragma unroll
      for (int kb = 0; kb < 20; ++kb) {
        if (kb < 19) {
          if (kb + 1 < 16) afn = ldh0(kb + 1);
          else {
            int k0 = (kb + 1 - 16) * 32 + l4 * 8;
#pragma unroll
            for (int j = 0; j < 8; ++j) afn[j] = (zrow == k0 + j) ? (short)0x3F80 : (short)0;
          }
        }
#pragma unroll
        for (int g = 0; g < 4; ++g)
          acc0[g] = __builtin_amdgcn_mfma_f32_16x16x32_bf16(afc, bq0[kb & 3][g], acc0[g], 0, 0, 0);
        if (kb + 4 < 20) {
#pragma unroll
          for (int g = 0; g < 4; ++g) bq0[kb & 3][g] = *(const bf16x8*)(bp0[g] + (kb + 4) * 32);
        }
        if (kb < 19) afc = afn;
      }
      u16 hb[4];
#pragma unroll
      for (int q = 0; q < 4; ++q) {
        float iv = acc0[0][q] + bias0[0], fv = acc0[1][q] + bias0[1];
        float gv = acc0[2][q] + bias0[2], ov = acc0[3][q] + bias0[3];
        float cn = sigf(fv) * c0s[q] + sigf(iv) * tanh_f(gv);
        float hn = sigf(ov) * tanh_f(cn);
        c0s[q] = cn; hb[q] = f2b(hn);
      }
      tstore(hb, h0buf + (tau & 1) * HB + row0 * 512);
    }
    __syncthreads();  // s2: h0 stores drained (vmcnt 0)
    if (tid == 0) {
      if (isC) fadd(fA);                       // h0(tau) published
      fpoll(fB, 17u + 17u * (u32)tau);         // h1(tau-2) stored & prior readers done
    }
    __syncthreads();  // s2b
    bool l1act = isC && tau >= 1 && tau <= TT;
    bool lgact = (!isC) && tau >= 2;
    f32x4 acc1[4] = {VZ, VZ, VZ, VZ};
    bf16x8 bq1[4][4];
    // ---- stage h1(tau-2) ----
    if (l1act || lgact) {
      const u16* src = h1buf + (tau & 1) * HB + row0 * 512;
#pragma unroll
      for (int it = 0; it < 8; ++it) {
        int i = it * 256 + tid, rr = i >> 6, kc = i & 63;
        *(bf16x8*)(h1s + rr * 512 + ((kc ^ (rr & 7)) * 8)) = ld_coh16(src + rr * 512 + kc * 8);
      }
    }
    // ---- L1 part 1: h0 input half (K 0..511), overlaps h1 staging ----
    if (l1act) {
#pragma unroll
      for (int p = 0; p < 4; ++p)
#pragma unroll
        for (int g = 0; g < 4; ++g) bq1[p][g] = *(const bf16x8*)(bp1[g] + p * 32);
      bf16x8 afc = ldh0(0), afn;
#pragma unroll
      for (int kb = 0; kb < 16; ++kb) {
        if (kb < 15) afn = ldh0(kb + 1);
#pragma unroll
        for (int g = 0; g < 4; ++g)
          acc1[g] = __builtin_amdgcn_mfma_f32_16x16x32_bf16(afc, bq1[kb & 3][g], acc1[g], 0, 0, 0);
#pragma unroll
        for (int g = 0; g < 4; ++g) bq1[kb & 3][g] = *(const bf16x8*)(bp1[g] + (kb + 4) * 32);
        if (kb < 15) afc = afn;
      }
    }
    __syncthreads();  // s3: h1s ready
    if (l1act) {
      // ---- L1 part 2: h1 recurrent half (K 512..1023) + epilogue ----
      bf16x8 afc = ldh1(0), afn;
#pragma unroll
      for (int kb = 16; kb < 32; ++kb) {
        int kl = kb - 16;
        if (kl < 15) afn = ldh1(kl + 1);
#pragma unroll
        for (int g = 0; g < 4; ++g)
          acc1[g] = __builtin_amdgcn_mfma_f32_16x16x32_bf16(afc, bq1[kb & 3][g], acc1[g], 0, 0, 0);
        if (kb + 4 < 32) {
#pragma unroll
          for (int g = 0; g < 4; ++g) bq1[kb & 3][g] = *(const bf16x8*)(bp1[g] + (kb + 4) * 32);
        }
        if (kl < 15) afc = afn;
      }
      u16 hb[4];
#pragma unroll
      for (int q = 0; q < 4; ++q) {
        float iv = acc1[0][q] + bias1[0], fv = acc1[1][q] + bias1[1];
        float gv = acc1[2][q] + bias1[2], ov = acc1[3][q] + bias1[3];
        float cn = sigf(fv) * c1s[q] + sigf(iv) * tanh_f(gv);
        float hn = sigf(ov) * tanh_f(cn);
        c1s[q] = cn; hb[q] = f2b(hn);
      }
      tstore(hb, h1buf + ((tau + 1) & 1) * HB + row0 * 512);
    } else if (lgact) {
      // ---- logits + NLL(tau-2) ----
      bf16x8 bqL[4][4];
#pragma unroll
      for (int p = 0; p < 4; ++p)
#pragma unroll
        for (int cb = 0; cb < 4; ++cb) bqL[p][cb] = *(const bf16x8*)(bpL[cb] + p * 32);
      f32x4 accL[4] = {VZ, VZ, VZ, VZ};
      bf16x8 afc = ldh1(0), afn;
#pragma unroll
      for (int kb = 0; kb < 16; ++kb) {
        if (kb < 15) afn = ldh1(kb + 1);
#pragma unroll
        for (int cb = 0; cb < 4; ++cb)
          accL[cb] = __builtin_amdgcn_mfma_f32_16x16x32_bf16(afc, bqL[kb & 3][cb], accL[cb], 0, 0, 0);
        if (kb + 4 < 16) {
#pragma unroll
          for (int cb = 0; cb < 4; ++cb) bqL[kb & 3][cb] = *(const bf16x8*)(bpL[cb] + (kb + 4) * 32);
        }
        if (kb < 15) afc = afn;
      }
      int t2 = tau - 2;
      float* mS = (float*)smem;          // overlay: logits WG never stages h0s
      float* sS = mS + 64;
      float* tS = sS + 64;
      float v[4][4];
#pragma unroll
      for (int cb = 0; cb < 4; ++cb)
#pragma unroll
        for (int q = 0; q < 4; ++q) v[cb][q] = accL[cb][q] + biasL[cb];
      float mp[4];
#pragma unroll
      for (int q = 0; q < 4; ++q) {
        float m = fmaxf(fmaxf(v[0][q], v[1][q]), fmaxf(v[2][q], v[3][q]));
        m = fmaxf(m, __shfl_xor(m, 1, 64)); m = fmaxf(m, __shfl_xor(m, 2, 64));
        m = fmaxf(m, __shfl_xor(m, 4, 64)); m = fmaxf(m, __shfl_xor(m, 8, 64));
        mp[q] = m;
      }
      if (l15 == 0) {
#pragma unroll
        for (int q = 0; q < 4; ++q) mS[(rb * 16 + l4 * 4 + q) * 2 + sub] = mp[q];
      }
      __syncthreads();
      float mm[4], sp[4], tp[4];
#pragma unroll
      for (int q = 0; q < 4; ++q) {
        int row = rb * 16 + l4 * 4 + q;
        mm[q] = fmaxf(mS[row * 2], mS[row * 2 + 1]);
        float s = 0.f;
#pragma unroll
        for (int cb = 0; cb < 4; ++cb) s += __expf(v[cb][q] - mm[q]);
        s += __shfl_xor(s, 1, 64); s += __shfl_xor(s, 2, 64);
        s += __shfl_xor(s, 4, 64); s += __shfl_xor(s, 8, 64);
        sp[q] = s;
        int zrow = z[(row0 + row) * TT + t2];
        float t = 0.f;
#pragma unroll
        for (int cb = 0; cb < 4; ++cb) {
          int col = sub * 64 + cb * 16 + l15;
          t += (col == zrow) ? v[cb][q] : 0.f;
        }
        t += __shfl_xor(t, 1, 64); t += __shfl_xor(t, 2, 64);
        t += __shfl_xor(t, 4, 64); t += __shfl_xor(t, 8, 64);
        tp[q] = t;
      }
      if (l15 == 0) {
#pragma unroll
        for (int q = 0; q < 4; ++q) {
          int row = rb * 16 + l4 * 4 + q;
          sS[row * 2 + sub] = sp[q]; tS[row * 2 + sub] = tp[q];
        }
      }
      __syncthreads();
      if (sub == 0) {
#pragma unroll
        for (int q = 0; q < 4; ++q) {
          int row = rb * 16 + l4 * 4 + q;
          float s = sS[row * 2] + sS[row * 2 + 1];
          float tv = tS[row * 2] + tS[row * 2 + 1];
          if ((float)t2 < nfl[q]) accN[q] += mm[q] + __logf(s) - tv;
        }
      }
    }
    __syncthreads();  // s4: h1 stores drained
    if (tid == 0) {
      fadd(fB);
      if (tau < TT + 1) fpoll(fA, 17u + 16u * (u32)(tau + 1));  // h0(tau) published by all
    }
    __syncthreads();
  }

  if (!isC && sub == 0 && l15 == 0) {
#pragma unroll
    for (int q = 0; q < 4; ++q)
      out[row0 + rb * 16 + l4 * 4 + q] = accN[q] * (1.0f / TT);
  }
}

extern "C" void kernel_launch(void* const* d_in, const int* in_sizes, int n_in,
                              void* d_out, int out_size, void* d_ws, size_t ws_size,
                              hipStream_t stream) {
  const float* wih0 = (const float*)d_in[0];
  const float* whh0 = (const float*)d_in[1];
  const float* bih0 = (const float*)d_in[2];
  const float* bhh0 = (const float*)d_in[3];
  const float* wih1 = (const float*)d_in[4];
  const float* whh1 = (const float*)d_in[5];
  const float* bih1 = (const float*)d_in[6];
  const float* bhh1 = (const float*)d_in[7];
  const float* wlinf = (const float*)d_in[8];
  const float* blin = (const float*)d_in[9];
  const int* z = (const int*)d_in[10];
  const int* nfr = (const int*)d_in[11];
  float* out = (float*)d_out;
  char* ws = (char*)d_ws;
  u16* wl0 = (u16*)(ws + WL0_OFF);
  u16* wl1 = (u16*)(ws + WL1_OFF);
  u16* wlin = (u16*)(ws + WLIN_OFF);
  u16* h0buf = (u16*)(ws + H0_OFF);
  u16* h1buf = (u16*)(ws + H1_OFF);
  u32* bars = (u32*)(ws + BAR_OFF);

  hipMemsetAsync(ws + BAR_OFF, 0, 2048, stream);
  const int NTOT = 2048 * 640 + 2048 * 1024 + 128 * 512;
  prep_kernel<<<dim3((NTOT + 255) / 256), dim3(256), 0, stream>>>(
      wih0, whh0, wih1, whh1, wlinf, wl0, wl1, wlin);
  lstm_kernel<<<dim3(NWG), dim3(256), 65536, stream>>>(
      bih0, bhh0, bih1, bhh1, blin, z, nfr, wl0, wl1, wlin, h0buf, h1buf, bars, out);
}

// Round 4
// 24709.840 us; speedup vs baseline: 1.1832x; 1.1832x over previous
//
#include <hip/hip_runtime.h>

#define TT 800

typedef __attribute__((ext_vector_type(8))) short bf16x8;
typedef __attribute__((ext_vector_type(4))) float f32x4;
typedef unsigned short u16;
typedef unsigned int u32;
typedef unsigned long long u64;

constexpr int TILES = 8, RT = 32, NCW = 128, NWG = 136;
constexpr size_t WL0_OFF  = 0;              // [2048][640] bf16
constexpr size_t WL1_OFF  = 2621440;        // [2048][1024] bf16
constexpr size_t WLIN_OFF = 6815744;        // [128][512] bf16
constexpr size_t H0_OFF   = 6946816;        // [2][256][512] bf16
constexpr size_t H1_OFF   = 7471104;        // [2][256][512] bf16
constexpr size_t BAR_OFF  = 7995392;        // 8 tiles * 256B flags
constexpr int HB = 256 * 512;

__device__ __forceinline__ u16 f2b(float x) {
  u32 u = __float_as_uint(x);
  return (u16)((u + 0x7FFFu + ((u >> 16) & 1u)) >> 16);   // RNE fp32->bf16
}
__device__ __forceinline__ float sigf(float x) { return 1.f / (1.f + __expf(-x)); }
__device__ __forceinline__ float tanh_f(float x) { float e = __expf(2.f * x); return 1.f - 2.f / (e + 1.f); }

// Coherent (cross-XCD) ops: sc0 sc1, bypass L1/L2, served at coherence point.
// Weights/z stay plain-cached (L2 warm across all ticks) — no fences anywhere.
__device__ __forceinline__ bf16x8 ld_coh16(const u16* p) {
  union { bf16x8 v; u64 q[2]; } u;
  u.q[0] = __hip_atomic_load((const u64*)p,     __ATOMIC_RELAXED, __HIP_MEMORY_SCOPE_AGENT);
  u.q[1] = __hip_atomic_load((const u64*)p + 1, __ATOMIC_RELAXED, __HIP_MEMORY_SCOPE_AGENT);
  return u.v;
}
__device__ __forceinline__ void st8(u64* p, u64 v) {
  __hip_atomic_store(p, v, __ATOMIC_RELAXED, __HIP_MEMORY_SCOPE_AGENT);
}
__device__ __forceinline__ void fadd(u32* f) {
  __hip_atomic_fetch_add(f, 1u, __ATOMIC_RELAXED, __HIP_MEMORY_SCOPE_AGENT);
}
__device__ __forceinline__ void fpoll(u32* f, u32 thr) {
  while (__hip_atomic_load(f, __ATOMIC_RELAXED, __HIP_MEMORY_SCOPE_AGENT) < thr)
    __builtin_amdgcn_s_sleep(1);
}

__global__ void prep_kernel(const float* __restrict__ wih0, const float* __restrict__ whh0,
                            const float* __restrict__ wih1, const float* __restrict__ whh1,
                            const float* __restrict__ wlinf,
                            u16* __restrict__ wl0, u16* __restrict__ wl1, u16* __restrict__ wlin) {
  int i = blockIdx.x * 256 + threadIdx.x;
  const int N0 = 2048 * 640, N1 = 2048 * 1024, N2 = 128 * 512;
  if (i < N0) {
    int col = i / 640, k = i - col * 640;
    float v = (k < 512) ? whh0[col * 512 + k] : wih0[col * 128 + (k - 512)];
    wl0[i] = f2b(v);
  } else if (i < N0 + N1) {
    int j = i - N0, col = j >> 10, k = j & 1023;
    float v = (k < 512) ? wih1[col * 512 + k] : whh1[col * 512 + (k - 512)];
    wl1[j] = f2b(v);
  } else if (i < N0 + N1 + N2) {
    int j = i - N0 - N1, col = j >> 9, k = j & 511;
    wlin[j] = f2b(wlinf[col * 512 + k]);
  }
}

// 136 persistent WGs, XCD-aware numbering (XCD = blockIdx % 8 round-robin):
//   wg in [0,128): compute WG. tile = wg>>4, w = wg&15. Owns hidden units
//     [w*32, w*32+32) of BOTH layers. Since 16 = 0 mod 8, XCD = w % 8:
//     each XCD hosts only 2 distinct weight slices (w=c and w=c+8, all 8
//     tiles) = ~850 KB -> L2-resident across all 800 ticks. This is the
//     round-4 fix: round-3's tile*17+w numbering scattered ~7 MB of slices
//     per XCD and thrashed L2 (FETCH 29 MB/tick).
//   wg in [128,136): logits WG for tile = wg-128 (one per XCD, +131 KB Wlin).
// Flags (monotonic, per tile): flagA bumped by 16 computes after h0-store;
// flagB bumped by all 17 after h1-store (computes) / h1-stage (logits).
// WAR safety: every consumer STAGES a buffer before bumping the flag the
// next-parity writer gates on, so "flag >= thr" implies all readers done.
__global__ __launch_bounds__(256, 1) void lstm_kernel(
    const float* __restrict__ bih0, const float* __restrict__ bhh0,
    const float* __restrict__ bih1, const float* __restrict__ bhh1,
    const float* __restrict__ blin,
    const int* __restrict__ z, const int* __restrict__ nfr,
    const u16* __restrict__ wl0, const u16* __restrict__ wl1, const u16* __restrict__ wlin,
    u16* __restrict__ h0buf, u16* __restrict__ h1buf,
    u32* __restrict__ bars, float* __restrict__ out) {
  extern __shared__ char smem[];
  u16* h0s = (u16*)smem;            // [32][512] swizzled, 32 KB
  u16* h1s = (u16*)smem + 16384;    // [32][512] swizzled, 32 KB
  const int wg = blockIdx.x;
  const bool isC = (wg < NCW);
  const int tile = isC ? (wg >> 4) : (wg - NCW);
  const int w = isC ? (wg & 15) : 16;
  const int tid = threadIdx.x, lane = tid & 63, wv = tid >> 6;
  const int l15 = lane & 15, l4 = lane >> 4;
  const int rb = wv >> 1, sub = wv & 1;
  const int row0 = tile * RT;
  u32* fA = bars + tile * 64;
  u32* fB = bars + tile * 64 + 16;
  const f32x4 VZ = {0.f, 0.f, 0.f, 0.f};

  const int r = rb * 16 + l15;      // A-row this lane reads
  const int rx = r & 7;
  const int rbase = r * 512;

  float c0s[4] = {0, 0, 0, 0}, c1s[4] = {0, 0, 0, 0}, accN[4] = {0, 0, 0, 0};
  float bias0[4], bias1[4], biasL[4], nfl[4];
  const u16 *bp0[4], *bp1[4], *bpL[4];
  if (isC) {
#pragma unroll
    for (int g = 0; g < 4; ++g) {
      int col = g * 512 + w * 32 + sub * 16 + l15;
      bias0[g] = bih0[col] + bhh0[col];
      bp0[g] = wl0 + (size_t)col * 640 + l4 * 8;
      bias1[g] = bih1[col] + bhh1[col];
      bp1[g] = wl1 + (size_t)col * 1024 + l4 * 8;
    }
  } else {
#pragma unroll
    for (int cb = 0; cb < 4; ++cb) {
      int col = sub * 64 + cb * 16 + l15;
      biasL[cb] = blin[col];
      bpL[cb] = wlin + (size_t)col * 512 + l4 * 8;
    }
#pragma unroll
    for (int q = 0; q < 4; ++q) nfl[q] = (float)nfr[row0 + rb * 16 + l4 * 4 + q];
  }

  // init: w==0 WG of each tile zeroes h0 slot1 + h1 slot0/1 tile slices.
  if (isC && w == 0) {
    u64* z0 = (u64*)(h0buf + HB + row0 * 512);
    u64* z1 = (u64*)(h1buf + row0 * 512);
    u64* z2 = (u64*)(h1buf + HB + row0 * 512);
    for (int k = tid; k < 2048; k += 256) { st8(z0 + k, 0); st8(z1 + k, 0); st8(z2 + k, 0); }
  }
  __syncthreads();
  if (tid == 0) { fadd(fA); fadd(fB); fpoll(fA, 17u); }
  __syncthreads();

  // in-wave 16-shfl transpose: (rows-in-q, unit-in-lane) -> 8B row-chunks
  auto tstore = [&](const u16 hb[4], u16* dst) {
    int srcb = (lane >> 4) * 16 + (lane & 3) * 4;
    int qn = (lane >> 2) & 3;
    u32 vo[4] = {0, 0, 0, 0};
#pragma unroll
    for (int q2 = 0; q2 < 4; ++q2) {
      int x = (int)hb[q2];
#pragma unroll
      for (int j = 0; j < 4; ++j) {
        int g = __shfl(x, srcb + j, 64);
        if (qn == q2) vo[j] = (u32)(u16)g;
      }
    }
    u64 pk = (u64)vo[0] | ((u64)vo[1] << 16) | ((u64)vo[2] << 32) | ((u64)vo[3] << 48);
    int Rl = rb * 16 + (lane >> 2);
    int U0 = w * 32 + sub * 16 + (lane & 3) * 4;
    st8((u64*)(dst + Rl * 512 + U0), pk);
  };
  auto ldh0 = [&](int kb) { return *(const bf16x8*)(h0s + rbase + (((kb * 4 + l4) ^ rx) * 8)); };
  auto ldh1 = [&](int kl) { return *(const bf16x8*)(h1s + rbase + (((kl * 4 + l4) ^ rx) * 8)); };

#pragma unroll 1
  for (int tau = 0; tau <= TT + 1; ++tau) {
    // ---- stage h0(tau-1) (compute WGs) ----
    if (isC && tau <= TT) {
      const u16* src = h0buf + ((tau + 1) & 1) * HB + row0 * 512;
#pragma unroll
      for (int it = 0; it < 8; ++it) {
        int i = it * 256 + tid, rr = i >> 6, kc = i & 63;
        *(bf16x8*)(h0s + rr * 512 + ((kc ^ (rr & 7)) * 8)) = ld_coh16(src + rr * 512 + kc * 8);
      }
    }
    __syncthreads();  // s1: h0s ready
    // ---- L0: h0(tau) ----
    if (isC && tau < TT) {
      int zrow = -1;
      if (tau >= 1) zrow = z[(row0 + r) * TT + (tau - 1)];
      bf16x8 bq0[4][4];
#pragma unroll
      for (int p = 0; p < 4; ++p)
#pragma unroll
        for (int g = 0; g < 4; ++g) bq0[p][g] = *(const bf16x8*)(bp0[g] + p * 32);
      f32x4 acc0[4] = {VZ, VZ, VZ, VZ};
      bf16x8 afc = ldh0(0), afn;
#pragma unroll
      for (int kb = 0; kb < 20; ++kb) {
        if (kb < 19) {
          if (kb + 1 < 16) afn = ldh0(kb + 1);
          else {
            int k0 = (kb + 1 - 16) * 32 + l4 * 8;
#pragma unroll
            for (int j = 0; j < 8; ++j) afn[j] = (zrow == k0 + j) ? (short)0x3F80 : (short)0;
          }
        }
#pragma unroll
        for (int g = 0; g < 4; ++g)
          acc0[g] = __builtin_amdgcn_mfma_f32_16x16x32_bf16(afc, bq0[kb & 3][g], acc0[g], 0, 0, 0);
        if (kb + 4 < 20) {
#pragma unroll
          for (int g = 0; g < 4; ++g) bq0[kb & 3][g] = *(const bf16x8*)(bp0[g] + (kb + 4) * 32);
        }
        if (kb < 19) afc = afn;
      }
      u16 hb[4];
#pragma unroll
      for (int q = 0; q < 4; ++q) {
        float iv = acc0[0][q] + bias0[0], fv = acc0[1][q] + bias0[1];
        float gv = acc0[2][q] + bias0[2], ov = acc0[3][q] + bias0[3];
        float cn = sigf(fv) * c0s[q] + sigf(iv) * tanh_f(gv);
        float hn = sigf(ov) * tanh_f(cn);
        c0s[q] = cn; hb[q] = f2b(hn);
      }
      tstore(hb, h0buf + (tau & 1) * HB + row0 * 512);
    }
    __syncthreads();  // s2: h0 stores drained (vmcnt 0)
    if (tid == 0) {
      if (isC) fadd(fA);                       // h0(tau) published
      fpoll(fB, 17u + 17u * (u32)tau);         // h1(tau-2) stored & prior readers done
    }
    __syncthreads();  // s2b
    bool l1act = isC && tau >= 1 && tau <= TT;
    bool lgact = (!isC) && tau >= 2;
    f32x4 acc1[4] = {VZ, VZ, VZ, VZ};
    bf16x8 bq1[4][4];
    // ---- stage h1(tau-2) ----
    if (l1act || lgact) {
      const u16* src = h1buf + (tau & 1) * HB + row0 * 512;
#pragma unroll
      for (int it = 0; it < 8; ++it) {
        int i = it * 256 + tid, rr = i >> 6, kc = i & 63;
        *(bf16x8*)(h1s + rr * 512 + ((kc ^ (rr & 7)) * 8)) = ld_coh16(src + rr * 512 + kc * 8);
      }
    }
    // ---- L1 part 1: h0 input half (K 0..511), overlaps h1 staging ----
    if (l1act) {
#pragma unroll
      for (int p = 0; p < 4; ++p)
#pragma unroll
        for (int g = 0; g < 4; ++g) bq1[p][g] = *(const bf16x8*)(bp1[g] + p * 32);
      bf16x8 afc = ldh0(0), afn;
#pragma unroll
      for (int kb = 0; kb < 16; ++kb) {
        if (kb < 15) afn = ldh0(kb + 1);
#pragma unroll
        for (int g = 0; g < 4; ++g)
          acc1[g] = __builtin_amdgcn_mfma_f32_16x16x32_bf16(afc, bq1[kb & 3][g], acc1[g], 0, 0, 0);
#pragma unroll
        for (int g = 0; g < 4; ++g) bq1[kb & 3][g] = *(const bf16x8*)(bp1[g] + (kb + 4) * 32);
        if (kb < 15) afc = afn;
      }
    }
    __syncthreads();  // s3: h1s ready
    if (l1act) {
      // ---- L1 part 2: h1 recurrent half (K 512..1023) + epilogue ----
      bf16x8 afc = ldh1(0), afn;
#pragma unroll
      for (int kb = 16; kb < 32; ++kb) {
        int kl = kb - 16;
        if (kl < 15) afn = ldh1(kl + 1);
#pragma unroll
        for (int g = 0; g < 4; ++g)
          acc1[g] = __builtin_amdgcn_mfma_f32_16x16x32_bf16(afc, bq1[kb & 3][g], acc1[g], 0, 0, 0);
        if (kb + 4 < 32) {
#pragma unroll
          for (int g = 0; g < 4; ++g) bq1[kb & 3][g] = *(const bf16x8*)(bp1[g] + (kb + 4) * 32);
        }
        if (kl < 15) afc = afn;
      }
      u16 hb[4];
#pragma unroll
      for (int q = 0; q < 4; ++q) {
        float iv = acc1[0][q] + bias1[0], fv = acc1[1][q] + bias1[1];
        float gv = acc1[2][q] + bias1[2], ov = acc1[3][q] + bias1[3];
        float cn = sigf(fv) * c1s[q] + sigf(iv) * tanh_f(gv);
        float hn = sigf(ov) * tanh_f(cn);
        c1s[q] = cn; hb[q] = f2b(hn);
      }
      tstore(hb, h1buf + ((tau + 1) & 1) * HB + row0 * 512);
    } else if (lgact) {
      // ---- logits + NLL(tau-2) ----
      bf16x8 bqL[4][4];
#pragma unroll
      for (int p = 0; p < 4; ++p)
#pragma unroll
        for (int cb = 0; cb < 4; ++cb) bqL[p][cb] = *(const bf16x8*)(bpL[cb] + p * 32);
      f32x4 accL[4] = {VZ, VZ, VZ, VZ};
      bf16x8 afc = ldh1(0), afn;
#pragma unroll
      for (int kb = 0; kb < 16; ++kb) {
        if (kb < 15) afn = ldh1(kb + 1);
#pragma unroll
        for (int cb = 0; cb < 4; ++cb)
          accL[cb] = __builtin_amdgcn_mfma_f32_16x16x32_bf16(afc, bqL[kb & 3][cb], accL[cb], 0, 0, 0);
        if (kb + 4 < 16) {
#pragma unroll
          for (int cb = 0; cb < 4; ++cb) bqL[kb & 3][cb] = *(const bf16x8*)(bpL[cb] + (kb + 4) * 32);
        }
        if (kb < 15) afc = afn;
      }
      int t2 = tau - 2;
      float* mS = (float*)smem;          // overlay: logits WG never stages h0s
      float* sS = mS + 64;
      float* tS = sS + 64;
      float v[4][4];
#pragma unroll
      for (int cb = 0; cb < 4; ++cb)
#pragma unroll
        for (int q = 0; q < 4; ++q) v[cb][q] = accL[cb][q] + biasL[cb];
      float mp[4];
#pragma unroll
      for (int q = 0; q < 4; ++q) {
        float m = fmaxf(fmaxf(v[0][q], v[1][q]), fmaxf(v[2][q], v[3][q]));
        m = fmaxf(m, __shfl_xor(m, 1, 64)); m = fmaxf(m, __shfl_xor(m, 2, 64));
        m = fmaxf(m, __shfl_xor(m, 4, 64)); m = fmaxf(m, __shfl_xor(m, 8, 64));
        mp[q] = m;
      }
      if (l15 == 0) {
#pragma unroll
        for (int q = 0; q < 4; ++q) mS[(rb * 16 + l4 * 4 + q) * 2 + sub] = mp[q];
      }
      __syncthreads();
      float mm[4], sp[4], tp[4];
#pragma unroll
      for (int q = 0; q < 4; ++q) {
        int row = rb * 16 + l4 * 4 + q;
        mm[q] = fmaxf(mS[row * 2], mS[row * 2 + 1]);
        float s = 0.f;
#pragma unroll
        for (int cb = 0; cb < 4; ++cb) s += __expf(v[cb][q] - mm[q]);
        s += __shfl_xor(s, 1, 64); s += __shfl_xor(s, 2, 64);
        s += __shfl_xor(s, 4, 64); s += __shfl_xor(s, 8, 64);
        sp[q] = s;
        int zrow = z[(row0 + row) * TT + t2];
        float t = 0.f;
#pragma unroll
        for (int cb = 0; cb < 4; ++cb) {
          int col = sub * 64 + cb * 16 + l15;
          t += (col == zrow) ? v[cb][q] : 0.f;
        }
        t += __shfl_xor(t, 1, 64); t += __shfl_xor(t, 2, 64);
        t += __shfl_xor(t, 4, 64); t += __shfl_xor(t, 8, 64);
        tp[q] = t;
      }
      if (l15 == 0) {
#pragma unroll
        for (int q = 0; q < 4; ++q) {
          int row = rb * 16 + l4 * 4 + q;
          sS[row * 2 + sub] = sp[q]; tS[row * 2 + sub] = tp[q];
        }
      }
      __syncthreads();
      if (sub == 0) {
#pragma unroll
        for (int q = 0; q < 4; ++q) {
          int row = rb * 16 + l4 * 4 + q;
          float s = sS[row * 2] + sS[row * 2 + 1];
          float tv = tS[row * 2] + tS[row * 2 + 1];
          if ((float)t2 < nfl[q]) accN[q] += mm[q] + __logf(s) - tv;
        }
      }
    }
    __syncthreads();  // s4: h1 stores drained
    if (tid == 0) {
      fadd(fB);
      if (tau < TT + 1) fpoll(fA, 17u + 16u * (u32)(tau + 1));  // h0(tau) published by all
    }
    __syncthreads();
  }

  if (!isC && sub == 0 && l15 == 0) {
#pragma unroll
    for (int q = 0; q < 4; ++q)
      out[row0 + rb * 16 + l4 * 4 + q] = accN[q] * (1.0f / TT);
  }
}

extern "C" void kernel_launch(void* const* d_in, const int* in_sizes, int n_in,
                              void* d_out, int out_size, void* d_ws, size_t ws_size,
                              hipStream_t stream) {
  const float* wih0 = (const float*)d_in[0];
  const float* whh0 = (const float*)d_in[1];
  const float* bih0 = (const float*)d_in[2];
  const float* bhh0 = (const float*)d_in[3];
  const float* wih1 = (const float*)d_in[4];
  const float* whh1 = (const float*)d_in[5];
  const float* bih1 = (const float*)d_in[6];
  const float* bhh1 = (const float*)d_in[7];
  const float* wlinf = (const float*)d_in[8];
  const float* blin = (const float*)d_in[9];
  const int* z = (const int*)d_in[10];
  const int* nfr = (const int*)d_in[11];
  float* out = (float*)d_out;
  char* ws = (char*)d_ws;
  u16* wl0 = (u16*)(ws + WL0_OFF);
  u16* wl1 = (u16*)(ws + WL1_OFF);
  u16* wlin = (u16*)(ws + WLIN_OFF);
  u16* h0buf = (u16*)(ws + H0_OFF);
  u16* h1buf = (u16*)(ws + H1_OFF);
  u32* bars = (u32*)(ws + BAR_OFF);

  hipMemsetAsync(ws + BAR_OFF, 0, 2048, stream);
  const int NTOT = 2048 * 640 + 2048 * 1024 + 128 * 512;
  prep_kernel<<<dim3((NTOT + 255) / 256), dim3(256), 0, stream>>>(
      wih0, whh0, wih1, whh1, wlinf, wl0, wl1, wlin);
  lstm_kernel<<<dim3(NWG), dim3(256), 65536, stream>>>(
      bih0, bhh0, bih1, bhh1, blin, z, nfr, wl0, wl1, wlin, h0buf, h1buf, bars, out);
}

// Round 5
// 9630.285 us; speedup vs baseline: 3.0358x; 2.5658x over previous
//
#include <hip/hip_runtime.h>

#define TT 800

typedef __attribute__((ext_vector_type(8))) short bf16x8;
typedef __attribute__((ext_vector_type(4))) float f32x4;
typedef unsigned short u16;
typedef unsigned int u32;
typedef unsigned long long u64;

constexpr int NCW = 128, NWG = 136, RT = 32;
constexpr size_t WL0_OFF  = 0;              // [2048][640] bf16
constexpr size_t WL1_OFF  = 2621440;        // [2048][1024] bf16
constexpr size_t WLIN_OFF = 6815744;        // [128][512] bf16
constexpr size_t H0_OFF   = 6946816;        // [2][256][512] bf16
constexpr size_t H1_OFF   = 7471104;        // [2][256][512] bf16
constexpr size_t BAR_OFF  = 7995392;        // 8 tiles * 128B flags
constexpr int HB = 256 * 512;
// LDS map (bytes): A region = 32 rows x 648 u16 (h0/h1 stage cols 0..511,
// one-hot cols 512..639, +8 pad for bank spread) = 41472.
// G region (gate/logit combine) = 32 x 129 f32 = 16512 @ 41472.
// P region (softmax partials) = 3 x 32 x 8 f32 = 3072 @ 57984. Total 61056.
constexpr int A_STRIDE = 648;
constexpr int G_OFF_B = 41472;
constexpr int P_OFF_B = 57984;
constexpr int LDS_BYTES = 61440;

__device__ __forceinline__ u16 f2b(float x) {
  u32 u = __float_as_uint(x);
  return (u16)((u + 0x7FFFu + ((u >> 16) & 1u)) >> 16);   // RNE fp32->bf16
}
__device__ __forceinline__ float sigf(float x) { return 1.f / (1.f + __expf(-x)); }
__device__ __forceinline__ float tanh_f(float x) { float e = __expf(2.f * x); return 1.f - 2.f / (e + 1.f); }

__device__ __forceinline__ u64 ld_coh8(const u64* p) {
  return __hip_atomic_load(p, __ATOMIC_RELAXED, __HIP_MEMORY_SCOPE_AGENT);
}
__device__ __forceinline__ void st_coh2(u16* p, u16 v) {
  __hip_atomic_store(p, v, __ATOMIC_RELAXED, __HIP_MEMORY_SCOPE_AGENT);
}
__device__ __forceinline__ void st_coh8(u64* p, u64 v) {
  __hip_atomic_store(p, v, __ATOMIC_RELAXED, __HIP_MEMORY_SCOPE_AGENT);
}
__device__ __forceinline__ void fadd(u32* f) {
  __hip_atomic_fetch_add(f, 1u, __ATOMIC_RELAXED, __HIP_MEMORY_SCOPE_AGENT);
}
__device__ __forceinline__ void fpoll(u32* f, u32 thr) {
  while (__hip_atomic_load(f, __ATOMIC_RELAXED, __HIP_MEMORY_SCOPE_AGENT) < thr)
    __builtin_amdgcn_s_sleep(1);
}

__global__ void prep_kernel(const float* __restrict__ wih0, const float* __restrict__ whh0,
                            const float* __restrict__ wih1, const float* __restrict__ whh1,
                            const float* __restrict__ wlinf,
                            u16* __restrict__ wl0, u16* __restrict__ wl1, u16* __restrict__ wlin) {
  int i = blockIdx.x * 256 + threadIdx.x;
  const int N0 = 2048 * 640, N1 = 2048 * 1024, N2 = 128 * 512;
  if (i < N0) {
    int col = i / 640, k = i - col * 640;
    float v = (k < 512) ? whh0[col * 512 + k] : wih0[col * 128 + (k - 512)];
    wl0[i] = f2b(v);
  } else if (i < N0 + N1) {
    int j = i - N0, col = j >> 10, k = j & 1023;
    float v = (k < 512) ? wih1[col * 512 + k] : whh1[col * 512 + (k - 512)];
    wl1[j] = f2b(v);
  } else if (i < N0 + N1 + N2) {
    int j = i - N0 - N1, col = j >> 9, k = j & 511;
    wlin[j] = f2b(wlinf[col * 512 + k]);
  }
}

// 136 persistent WGs, XCD-aware (XCD = blockIdx % 8):
//   wg<128: compute. tile=wg>>4, w=wg&15 -> XCD=w%8: 2 distinct L0 weight
//     slices per XCD (L2-resident, round-4-verified). Owns units
//     [w*32,w*32+32) of both layers. L1+Wlin weights live in REGISTERS.
//   wg>=128: logits WG for tile wg-128.
// Re-timed pipeline, ONE flag/tile/tick: tick tau consumes ONLY data
// published by end of tick tau-1: h0(tau-1) [slot (tau-1)&1], h1(tau-2)
// [slot tau&1]. Produces h0(tau) [slot tau&1], h1(tau-1) [slot (tau+1)&1].
// Flag F: each of 17 WGs adds 1 at tick end (after staging + stores
// drained). Poll at tick start: F >= 17*(tau+1). WAR safe: a writer at
// tick tau passed F>=17*tau, which requires every reader's tick-(tau-1)
// staging of the slot being overwritten.
__global__ __launch_bounds__(256, 1) void lstm_kernel(
    const float* __restrict__ bih0, const float* __restrict__ bhh0,
    const float* __restrict__ bih1, const float* __restrict__ bhh1,
    const float* __restrict__ blin,
    const int* __restrict__ z, const int* __restrict__ nfr,
    const u16* __restrict__ wl0, const u16* __restrict__ wl1, const u16* __restrict__ wlin,
    u16* __restrict__ h0buf, u16* __restrict__ h1buf,
    u32* __restrict__ bars, float* __restrict__ out) {
  extern __shared__ char smem[];
  u16* A = (u16*)smem;
  float* Gf = (float*)(smem + G_OFF_B);
  float* Pm = (float*)(smem + P_OFF_B);
  float* Ps = Pm + 256;
  float* Pt = Ps + 256;
  const int wg = blockIdx.x;
  const bool isC = (wg < NCW);
  const int tile = isC ? (wg >> 4) : (wg - NCW);
  const int w = isC ? (wg & 15) : 16;
  const int tid = threadIdx.x, lane = tid & 63, wv = tid >> 6;
  const int l15 = lane & 15, l4 = lane >> 4;
  const int row0 = tile * RT;
  u32* F = bars + tile * 32;
  const f32x4 VZ = {0.f, 0.f, 0.f, 0.f};
  const int cu = tid & 31;          // cell: unit within WG slice
  const int rg = tid >> 5;          // cell: row group (4 rows)

  float c0s[4] = {0, 0, 0, 0}, c1s[4] = {0, 0, 0, 0};
  float accN = 0.f, nflv = 0.f;
  float bias0c[2], bias1c[2], biasLc[2];
  const u16* bpL0[2];
  bf16x8 bq1R[64];                  // L1 weights pinned: 2 cb x 32 kb, 256 VGPR
  bf16x8 wlR[32];                   // logits: 2 cb x 16 kb, 128 VGPR

  if (isC) {
#pragma unroll
    for (int cb = 0; cb < 2; ++cb) {
      int colL0 = wv * 512 + w * 32 + cb * 16 + l15;  // gate wv, half cb
      bias0c[cb] = bih0[colL0] + bhh0[colL0];
      bpL0[cb] = wl0 + (size_t)colL0 * 640 + l4 * 8;
      bias1c[cb] = bih1[colL0] + bhh1[colL0];
      const u16* b1 = wl1 + (size_t)colL0 * 1024 + l4 * 8;
#pragma unroll
      for (int kb = 0; kb < 32; ++kb) bq1R[cb * 32 + kb] = *(const bf16x8*)(b1 + kb * 32);
    }
  } else {
#pragma unroll
    for (int cb = 0; cb < 2; ++cb) {
      int colV = wv * 32 + cb * 16 + l15;
      biasLc[cb] = blin[colV];
      const u16* bL = wlin + (size_t)colV * 512 + l4 * 8;
#pragma unroll
      for (int kb = 0; kb < 16; ++kb) wlR[cb * 16 + kb] = *(const bf16x8*)(bL + kb * 32);
    }
    if (rg == 0) nflv = (float)nfr[row0 + cu];  // thread (r=cu, k=0)
  }

  // init: w==0 zeroes h0 slot1 + h1 slot0/1 tile slices (coherent).
  if (isC && w == 0) {
    u64* z0 = (u64*)(h0buf + HB + row0 * 512);
    u64* z1 = (u64*)(h1buf + row0 * 512);
    u64* z2 = (u64*)(h1buf + HB + row0 * 512);
    for (int k = tid; k < 2048; k += 256) { st_coh8(z0 + k, 0); st_coh8(z1 + k, 0); st_coh8(z2 + k, 0); }
  }
  __syncthreads();
  if (tid == 0) fadd(F);

  auto ldA = [&](int rb, int kb) {
    return *(const bf16x8*)(A + (rb * 16 + l15) * A_STRIDE + kb * 32 + l4 * 8);
  };

#pragma unroll 1
  for (int tau = 0; tau <= TT + 1; ++tau) {
    if (tid == 0) fpoll(F, 17u * (u32)(tau + 1));
    __syncthreads();  // poll done; tick inputs published
    const u16* h0src = h0buf + ((tau + 1) & 1) * HB + row0 * 512;
    const u16* h1src = h1buf + (tau & 1) * HB + row0 * 512;

    if (isC) {
      // ---- stage h0(tau-1): batched coherent loads -> LDS ----
      if (tau <= TT) {
        u64 ta[8], tb[8];
        const u64* s64 = (const u64*)h0src;
#pragma unroll
        for (int c = 0; c < 8; ++c) {
          int li = c * 256 + tid;
          ta[c] = ld_coh8(s64 + li * 2); tb[c] = ld_coh8(s64 + li * 2 + 1);
        }
#pragma unroll
        for (int c = 0; c < 8; ++c) {
          int li = c * 256 + tid, row = li >> 6, cc = li & 63;
          u64* d = (u64*)(A + row * A_STRIDE + cc * 8);
          d[0] = ta[c]; d[1] = tb[c];
        }
        // one-hot block (cols 512..639), built zero+bit in one pass
#pragma unroll
        for (int c = 0; c < 4; ++c) {
          int i = c * 256 + tid, row = i >> 5, cc = i & 31;
          u64 val = 0;
          if (tau >= 1) {
            int zv = z[(row0 + row) * TT + (tau - 1)];
            if ((zv >> 2) == cc) val = 0x3F80ull << ((zv & 3) * 16);
          }
          *(u64*)(A + row * A_STRIDE + 512 + cc * 4) = val;
        }
      }
      __syncthreads();  // A(h0 + onehot) ready
      // ---- L0: h0(tau) = cell(W_l0 . [h0(tau-1); onehot(z(tau-1))]) ----
      if (tau < TT) {
        bf16x8 br[4][2];
#pragma unroll
        for (int p = 0; p < 4; ++p)
#pragma unroll
          for (int cb = 0; cb < 2; ++cb) br[p][cb] = *(const bf16x8*)(bpL0[cb] + p * 32);
        f32x4 acc0[2][2] = {{VZ, VZ}, {VZ, VZ}};
#pragma unroll
        for (int kb = 0; kb < 20; ++kb) {
          bf16x8 a0 = ldA(0, kb), a1 = ldA(1, kb);
#pragma unroll
          for (int cb = 0; cb < 2; ++cb) {
            acc0[0][cb] = __builtin_amdgcn_mfma_f32_16x16x32_bf16(a0, br[kb & 3][cb], acc0[0][cb], 0, 0, 0);
            acc0[1][cb] = __builtin_amdgcn_mfma_f32_16x16x32_bf16(a1, br[kb & 3][cb], acc0[1][cb], 0, 0, 0);
          }
          if (kb + 4 < 20) {
#pragma unroll
            for (int cb = 0; cb < 2; ++cb) br[kb & 3][cb] = *(const bf16x8*)(bpL0[cb] + (kb + 4) * 32);
          }
        }
        // gate pre-acts -> G (wave wv owns gate wv)
#pragma unroll
        for (int rb = 0; rb < 2; ++rb)
#pragma unroll
          for (int cb = 0; cb < 2; ++cb)
#pragma unroll
            for (int q = 0; q < 4; ++q)
              Gf[(rb * 16 + l4 * 4 + q) * 129 + wv * 32 + cb * 16 + l15] = acc0[rb][cb][q] + bias0c[cb];
      }
      __syncthreads();  // G0 ready
      if (tau < TT) {
        u16* h0w = h0buf + (tau & 1) * HB + row0 * 512;
#pragma unroll
        for (int q = 0; q < 4; ++q) {
          int row = rg * 4 + q;
          float gi = Gf[row * 129 + cu], gf = Gf[row * 129 + 32 + cu];
          float gg = Gf[row * 129 + 64 + cu], go = Gf[row * 129 + 96 + cu];
          float cn = sigf(gf) * c0s[q] + sigf(gi) * tanh_f(gg);
          float hn = sigf(go) * tanh_f(cn);
          c0s[q] = cn;
          st_coh2(h0w + row * 512 + w * 32 + cu, f2b(hn));
        }
      }
      // ---- L1: h1(tau-1). Issue h1(tau-2) loads, overlap with part 1 ----
      bool l1act = (tau >= 1 && tau <= TT);
      u64 ta[8], tb[8];
      if (l1act) {
        const u64* s64 = (const u64*)h1src;
#pragma unroll
        for (int c = 0; c < 8; ++c) {
          int li = c * 256 + tid;
          ta[c] = ld_coh8(s64 + li * 2); tb[c] = ld_coh8(s64 + li * 2 + 1);
        }
      }
      f32x4 acc1[2][2] = {{VZ, VZ}, {VZ, VZ}};
      if (l1act) {
        // part 1: K 0..511 from A (h0(tau-1)), weights from registers
#pragma unroll
        for (int kb = 0; kb < 16; ++kb) {
          bf16x8 a0 = ldA(0, kb), a1 = ldA(1, kb);
#pragma unroll
          for (int cb = 0; cb < 2; ++cb) {
            acc1[0][cb] = __builtin_amdgcn_mfma_f32_16x16x32_bf16(a0, bq1R[cb * 32 + kb], acc1[0][cb], 0, 0, 0);
            acc1[1][cb] = __builtin_amdgcn_mfma_f32_16x16x32_bf16(a1, bq1R[cb * 32 + kb], acc1[1][cb], 0, 0, 0);
          }
        }
      }
      __syncthreads();  // all waves done reading A(h0)
      if (l1act) {
#pragma unroll
        for (int c = 0; c < 8; ++c) {
          int li = c * 256 + tid, row = li >> 6, cc = li & 63;
          u64* d = (u64*)(A + row * A_STRIDE + cc * 8);
          d[0] = ta[c]; d[1] = tb[c];
        }
      }
      __syncthreads();  // A(h1(tau-2)) ready
      if (l1act) {
#pragma unroll
        for (int kb = 16; kb < 32; ++kb) {
          bf16x8 a0 = ldA(0, kb - 16), a1 = ldA(1, kb - 16);
#pragma unroll
          for (int cb = 0; cb < 2; ++cb) {
            acc1[0][cb] = __builtin_amdgcn_mfma_f32_16x16x32_bf16(a0, bq1R[cb * 32 + kb], acc1[0][cb], 0, 0, 0);
            acc1[1][cb] = __builtin_amdgcn_mfma_f32_16x16x32_bf16(a1, bq1R[cb * 32 + kb], acc1[1][cb], 0, 0, 0);
          }
        }
#pragma unroll
        for (int rb = 0; rb < 2; ++rb)
#pragma unroll
          for (int cb = 0; cb < 2; ++cb)
#pragma unroll
            for (int q = 0; q < 4; ++q)
              Gf[(rb * 16 + l4 * 4 + q) * 129 + wv * 32 + cb * 16 + l15] = acc1[rb][cb][q] + bias1c[cb];
      }
      __syncthreads();  // G1 ready
      if (l1act) {
        u16* h1w = h1buf + ((tau + 1) & 1) * HB + row0 * 512;
#pragma unroll
        for (int q = 0; q < 4; ++q) {
          int row = rg * 4 + q;
          float gi = Gf[row * 129 + cu], gf = Gf[row * 129 + 32 + cu];
          float gg = Gf[row * 129 + 64 + cu], go = Gf[row * 129 + 96 + cu];
          float cn = sigf(gf) * c1s[q] + sigf(gi) * tanh_f(gg);
          float hn = sigf(go) * tanh_f(cn);
          c1s[q] = cn;
          st_coh2(h1w + row * 512 + w * 32 + cu, f2b(hn));
        }
      }
      __syncthreads();  // drain coherent stores (vmcnt 0) before flag
      if (tid == 0) fadd(F);
    } else {
      // ---------------- logits WG: NLL(tau-2) ----------------
      bool lgact = (tau >= 2);
      if (lgact) {
        u64 ta[8], tb[8];
        const u64* s64 = (const u64*)h1src;
#pragma unroll
        for (int c = 0; c < 8; ++c) {
          int li = c * 256 + tid;
          ta[c] = ld_coh8(s64 + li * 2); tb[c] = ld_coh8(s64 + li * 2 + 1);
        }
#pragma unroll
        for (int c = 0; c < 8; ++c) {
          int li = c * 256 + tid, row = li >> 6, cc = li & 63;
          u64* d = (u64*)(A + row * A_STRIDE + cc * 8);
          d[0] = ta[c]; d[1] = tb[c];
        }
      }
      __syncthreads();
      if (lgact) {
        f32x4 accL[2][2] = {{VZ, VZ}, {VZ, VZ}};
#pragma unroll
        for (int kb = 0; kb < 16; ++kb) {
          bf16x8 a0 = ldA(0, kb), a1 = ldA(1, kb);
#pragma unroll
          for (int cb = 0; cb < 2; ++cb) {
            accL[0][cb] = __builtin_amdgcn_mfma_f32_16x16x32_bf16(a0, wlR[cb * 16 + kb], accL[0][cb], 0, 0, 0);
            accL[1][cb] = __builtin_amdgcn_mfma_f32_16x16x32_bf16(a1, wlR[cb * 16 + kb], accL[1][cb], 0, 0, 0);
          }
        }
#pragma unroll
        for (int rb = 0; rb < 2; ++rb)
#pragma unroll
          for (int cb = 0; cb < 2; ++cb)
#pragma unroll
            for (int q = 0; q < 4; ++q)
              Gf[(rb * 16 + l4 * 4 + q) * 129 + wv * 32 + cb * 16 + l15] = accL[rb][cb][q] + biasLc[cb];
      }
      __syncthreads();
      if (lgact) {
        int t2 = tau - 2;
        int r = cu, k = rg;              // 8 threads per row
        float mloc = -3.4e38f;
        float vloc[16];
#pragma unroll
        for (int j = 0; j < 16; ++j) {
          vloc[j] = Gf[r * 129 + k * 16 + j];
          mloc = fmaxf(mloc, vloc[j]);
        }
        Pm[r * 8 + k] = mloc;
        __syncthreads();
        float mrow = Pm[r * 8];
#pragma unroll
        for (int j = 1; j < 8; ++j) mrow = fmaxf(mrow, Pm[r * 8 + j]);
        int zr = z[(row0 + r) * TT + t2];
        float sloc = 0.f, tloc = 0.f;
#pragma unroll
        for (int j = 0; j < 16; ++j) {
          sloc += __expf(vloc[j] - mrow);
          tloc += (k * 16 + j == zr) ? vloc[j] : 0.f;
        }
        Ps[r * 8 + k] = sloc; Pt[r * 8 + k] = tloc;
        __syncthreads();
        if (k == 0) {
          float s = 0.f, tv = 0.f;
#pragma unroll
          for (int j = 0; j < 8; ++j) { s += Ps[r * 8 + j]; tv += Pt[r * 8 + j]; }
          if ((float)t2 < nflv) accN += mrow + __logf(s) - tv;
        }
      }
      __syncthreads();
      if (tid == 0) fadd(F);
    }
  }

  if (!isC && rg == 0) out[row0 + cu] = accN * (1.0f / TT);
}

extern "C" void kernel_launch(void* const* d_in, const int* in_sizes, int n_in,
                              void* d_out, int out_size, void* d_ws, size_t ws_size,
                              hipStream_t stream) {
  const float* wih0 = (const float*)d_in[0];
  const float* whh0 = (const float*)d_in[1];
  const float* bih0 = (const float*)d_in[2];
  const float* bhh0 = (const float*)d_in[3];
  const float* wih1 = (const float*)d_in[4];
  const float* whh1 = (const float*)d_in[5];
  const float* bih1 = (const float*)d_in[6];
  const float* bhh1 = (const float*)d_in[7];
  const float* wlinf = (const float*)d_in[8];
  const float* blin = (const float*)d_in[9];
  const int* z = (const int*)d_in[10];
  const int* nfr = (const int*)d_in[11];
  float* out = (float*)d_out;
  char* ws = (char*)d_ws;
  u16* wl0 = (u16*)(ws + WL0_OFF);
  u16* wl1 = (u16*)(ws + WL1_OFF);
  u16* wlin = (u16*)(ws + WLIN_OFF);
  u16* h0buf = (u16*)(ws + H0_OFF);
  u16* h1buf = (u16*)(ws + H1_OFF);
  u32* bars = (u32*)(ws + BAR_OFF);

  hipMemsetAsync(ws + BAR_OFF, 0, 2048, stream);
  const int NTOT = 2048 * 640 + 2048 * 1024 + 128 * 512;
  prep_kernel<<<dim3((NTOT + 255) / 256), dim3(256), 0, stream>>>(
      wih0, whh0, wih1, whh1, wlinf, wl0, wl1, wlin);
  lstm_kernel<<<dim3(NWG), dim3(256), LDS_BYTES, stream>>>(
      bih0, bhh0, bih1, bhh1, blin, z, nfr, wl0, wl1, wlin, h0buf, h1buf, bars, out);
}

// Round 6
// 8930.607 us; speedup vs baseline: 3.2737x; 1.0783x over previous
//
#include <hip/hip_runtime.h>

#define TT 800

typedef __attribute__((ext_vector_type(8))) short bf16x8;
typedef __attribute__((ext_vector_type(4))) float f32x4;
typedef unsigned short u16;
typedef unsigned int u32;
typedef unsigned long long u64;

constexpr int NCW = 128, NWG = 136, RT = 32;
constexpr size_t WL0A_OFF = 0;              // [2048][512] bf16 = 2,097,152 (W_hh0, K-major)
constexpr size_t WL0B_OFF = 2097152;        // [128][2048] bf16 = 524,288  (W_ih0^T row-gather)
constexpr size_t WL1_OFF  = 2621440;        // [2048][1024] bf16
constexpr size_t WLIN_OFF = 6815744;        // [128][512] bf16
constexpr size_t H0_OFF   = 6946816;        // [2][256][512] bf16
constexpr size_t H1_OFF   = 7471104;        // [2][256][512] bf16
constexpr size_t BAR_OFF  = 7995392;        // 8 tiles * 128B flags
constexpr int HB = 256 * 512;
// LDS: A = 32 rows x 520 u16 = 33280 B; Gf = 32 x 129 f32 = 16512 B @33280;
// P = 3 x 256 f32 = 3072 B @49792. Total 52864 (<64K, no opt-in needed).
constexpr int A_ST = 520;
constexpr int G_OFF_B = 33280;
constexpr int P_OFF_B = 49792;
constexpr int LDS_BYTES = 53248;

__device__ __forceinline__ u16 f2b(float x) {
  u32 u = __float_as_uint(x);
  return (u16)((u + 0x7FFFu + ((u >> 16) & 1u)) >> 16);   // RNE fp32->bf16
}
__device__ __forceinline__ float b2f(u16 v) { return __uint_as_float(((u32)v) << 16); }
__device__ __forceinline__ float sigf(float x) { return 1.f / (1.f + __expf(-x)); }
__device__ __forceinline__ float tanh_f(float x) { float e = __expf(2.f * x); return 1.f - 2.f / (e + 1.f); }

__device__ __forceinline__ u64 ld_coh8(const u64* p) {
  return __hip_atomic_load(p, __ATOMIC_RELAXED, __HIP_MEMORY_SCOPE_AGENT);
}
__device__ __forceinline__ void st_coh8(u64* p, u64 v) {
  __hip_atomic_store(p, v, __ATOMIC_RELAXED, __HIP_MEMORY_SCOPE_AGENT);
}
__device__ __forceinline__ void fadd(u32* f) {
  __hip_atomic_fetch_add(f, 1u, __ATOMIC_RELAXED, __HIP_MEMORY_SCOPE_AGENT);
}
__device__ __forceinline__ void fpoll(u32* f, u32 thr) {
  while (__hip_atomic_load(f, __ATOMIC_RELAXED, __HIP_MEMORY_SCOPE_AGENT) < thr)
    __builtin_amdgcn_s_sleep(1);
}

__global__ void prep_kernel(const float* __restrict__ wih0, const float* __restrict__ whh0,
                            const float* __restrict__ wih1, const float* __restrict__ whh1,
                            const float* __restrict__ wlinf,
                            u16* __restrict__ wl0a, u16* __restrict__ wl0b,
                            u16* __restrict__ wl1, u16* __restrict__ wlin) {
  int i = blockIdx.x * 256 + threadIdx.x;
  const int NA = 2048 * 512, NB = 128 * 2048, N1 = 2048 * 1024, N2 = 128 * 512;
  if (i < NA) {
    int col = i >> 9, k = i & 511;
    wl0a[i] = f2b(whh0[col * 512 + k]);
  } else if (i < NA + NB) {
    int j = i - NA, k = j >> 11, col = j & 2047;
    wl0b[j] = f2b(wih0[col * 128 + k]);
  } else if (i < NA + NB + N1) {
    int j = i - NA - NB, col = j >> 10, k = j & 1023;
    float v = (k < 512) ? wih1[col * 512 + k] : whh1[col * 512 + (k - 512)];
    wl1[j] = f2b(v);
  } else if (i < NA + NB + N1 + N2) {
    int j = i - NA - NB - N1, col = j >> 9, k = j & 511;
    wlin[j] = f2b(wlinf[col * 512 + k]);
  }
}

// 136 persistent WGs, XCD-aware (XCD = blockIdx % 8):
//   wg<128: compute. tile=wg>>4, w=wg&15 (XCD=w%8: 2 weight slices/XCD,
//     L2-resident — round-4-verified). Owns units [w*32,+32) of both layers.
//     ALL weights pinned in registers: L1 (bq1R, 256 reg -> AGPR half of the
//     unified file), L0 W_hh0 (bq0R, 128 reg). W_ih0 contribution is a
//     row-GATHER from wl0b added in the cell epilogue (one-hot MFMA removed).
//     Zero per-tick weight streaming.
//   wg>=128: logits WG for tile wg-128; bumps the flag right after h1
//     staging (its only cross-WG obligation) -> off the tick critical path.
// One flag/tile/tick (round-5 protocol, WAR analysis unchanged): tick tau
// consumes h0(tau-1) [slot (tau-1)&1] and h1(tau-2) [slot tau&1]; produces
// h0(tau) [slot tau&1], h1(tau-1) [slot (tau+1)&1]. Poll F>=17*(tau+1).
__global__ __launch_bounds__(256, 1) void lstm_kernel(
    const float* __restrict__ bih0, const float* __restrict__ bhh0,
    const float* __restrict__ bih1, const float* __restrict__ bhh1,
    const float* __restrict__ blin,
    const int* __restrict__ z, const int* __restrict__ nfr,
    const u16* __restrict__ wl0a, const u16* __restrict__ wl0b,
    const u16* __restrict__ wl1, const u16* __restrict__ wlin,
    u16* __restrict__ h0buf, u16* __restrict__ h1buf,
    u32* __restrict__ bars, float* __restrict__ out) {
  extern __shared__ char smem[];
  u16* A = (u16*)smem;
  float* Gf = (float*)(smem + G_OFF_B);
  float* Pm = (float*)(smem + P_OFF_B);
  float* Ps = Pm + 256;
  float* Pt = Ps + 256;
  const int wg = blockIdx.x;
  const bool isC = (wg < NCW);
  const int tile = isC ? (wg >> 4) : (wg - NCW);
  const int w = isC ? (wg & 15) : 16;
  const int tid = threadIdx.x, lane = tid & 63, wv = tid >> 6;
  const int l15 = lane & 15, l4 = lane >> 4;
  const int row0 = tile * RT;
  u32* F = bars + tile * 32;
  const f32x4 VZ = {0.f, 0.f, 0.f, 0.f};
  // cell-phase mapping: thread -> (row rC, 4 consecutive units u0C..+3)
  const int rC = tid >> 3, u0C = (tid & 7) * 4;
  // logits softmax mapping
  const int cuL = tid & 31, rgL = tid >> 5;

  float c0s[4] = {0, 0, 0, 0}, c1s[4] = {0, 0, 0, 0};
  float accN = 0.f, nflv = 0.f;
  float bias0c[2], bias1c[2], biasLc[2];
  bf16x8 bq0R[32];                  // L0 W_hh0: 2 cb x 16 kb = 128 reg
  bf16x8 bq1R[64];                  // L1: 2 cb x 32 kb = 256 reg (AGPR)
  bf16x8 wlR[32];                   // logits: 2 cb x 16 kb (shares slots w/ bq0R path)

  if (isC) {
#pragma unroll
    for (int cb = 0; cb < 2; ++cb) {
      int col = wv * 512 + w * 32 + cb * 16 + l15;   // gate wv, half cb
      bias0c[cb] = bih0[col] + bhh0[col];
      bias1c[cb] = bih1[col] + bhh1[col];
      const u16* b0 = wl0a + (size_t)col * 512 + l4 * 8;
#pragma unroll
      for (int kb = 0; kb < 16; ++kb) bq0R[cb * 16 + kb] = *(const bf16x8*)(b0 + kb * 32);
      const u16* b1 = wl1 + (size_t)col * 1024 + l4 * 8;
#pragma unroll
      for (int kb = 0; kb < 32; ++kb) bq1R[cb * 32 + kb] = *(const bf16x8*)(b1 + kb * 32);
    }
  } else {
#pragma unroll
    for (int cb = 0; cb < 2; ++cb) {
      int colV = wv * 32 + cb * 16 + l15;
      biasLc[cb] = blin[colV];
      const u16* bL = wlin + (size_t)colV * 512 + l4 * 8;
#pragma unroll
      for (int kb = 0; kb < 16; ++kb) wlR[cb * 16 + kb] = *(const bf16x8*)(bL + kb * 32);
    }
    if (rgL == 0) nflv = (float)nfr[row0 + cuL];
  }

  if (isC && w == 0) {
    u64* z0 = (u64*)(h0buf + HB + row0 * 512);
    u64* z1 = (u64*)(h1buf + row0 * 512);
    u64* z2 = (u64*)(h1buf + HB + row0 * 512);
    for (int k = tid; k < 2048; k += 256) { st_coh8(z0 + k, 0); st_coh8(z1 + k, 0); st_coh8(z2 + k, 0); }
  }
  __syncthreads();
  if (tid == 0) fadd(F);

  auto ldA = [&](int rb, int kb) {
    return *(const bf16x8*)(A + (rb * 16 + l15) * A_ST + kb * 32 + l4 * 8);
  };

#pragma unroll 1
  for (int tau = 0; tau <= TT + 1; ++tau) {
    if (tid == 0) fpoll(F, 17u * (u32)(tau + 1));
    __syncthreads();  // B1: tick inputs published
    const u16* h0src = h0buf + ((tau + 1) & 1) * HB + row0 * 512;
    const u64* h1s64 = (const u64*)(h1buf + (tau & 1) * HB + row0 * 512);
    const bool l0act = isC && (tau < TT);
    const bool l1act = isC && (tau >= 1 && tau <= TT);

    if (isC) {
      // ---- stage h0(tau-1): 16 batched coherent loads -> A ----
      if (tau <= TT) {
        u64 ta[8], tb[8];
        const u64* s64 = (const u64*)h0src;
#pragma unroll
        for (int c = 0; c < 8; ++c) {
          int li = c * 256 + tid;
          ta[c] = ld_coh8(s64 + li * 2); tb[c] = ld_coh8(s64 + li * 2 + 1);
        }
#pragma unroll
        for (int c = 0; c < 8; ++c) {
          int li = c * 256 + tid, row = li >> 6, cc = li & 63;
          u64* d = (u64*)(A + row * A_ST + cc * 8);
          d[0] = ta[c]; d[1] = tb[c];
        }
      }
      // issue h1(tau-2) batch1 (rows 0..15) — in flight across L0+p1 MFMA
      u64 ha[4], hb[4];
      if (l1act) {
#pragma unroll
        for (int c = 0; c < 4; ++c) {
          int li = c * 256 + tid;
          ha[c] = ld_coh8(h1s64 + li * 2); hb[c] = ld_coh8(h1s64 + li * 2 + 1);
        }
      }
      __syncthreads();  // B2: A(h0) ready

      f32x4 acc0[2][2] = {{VZ, VZ}, {VZ, VZ}};
      f32x4 acc1[2][2] = {{VZ, VZ}, {VZ, VZ}};
      if (l0act) {
#pragma unroll
        for (int kb = 0; kb < 16; ++kb) {
          bf16x8 a0 = ldA(0, kb), a1 = ldA(1, kb);
#pragma unroll
          for (int cb = 0; cb < 2; ++cb) {
            acc0[0][cb] = __builtin_amdgcn_mfma_f32_16x16x32_bf16(a0, bq0R[cb * 16 + kb], acc0[0][cb], 0, 0, 0);
            acc0[1][cb] = __builtin_amdgcn_mfma_f32_16x16x32_bf16(a1, bq0R[cb * 16 + kb], acc0[1][cb], 0, 0, 0);
          }
        }
      }
      if (l1act) {
        // L1 part 1: K 0..511 (h0(tau-1)) from A, weights in registers
#pragma unroll
        for (int kb = 0; kb < 16; ++kb) {
          bf16x8 a0 = ldA(0, kb), a1 = ldA(1, kb);
#pragma unroll
          for (int cb = 0; cb < 2; ++cb) {
            acc1[0][cb] = __builtin_amdgcn_mfma_f32_16x16x32_bf16(a0, bq1R[cb * 32 + kb], acc1[0][cb], 0, 0, 0);
            acc1[1][cb] = __builtin_amdgcn_mfma_f32_16x16x32_bf16(a1, bq1R[cb * 32 + kb], acc1[1][cb], 0, 0, 0);
          }
        }
      }
      if (l0act) {
#pragma unroll
        for (int rb = 0; rb < 2; ++rb)
#pragma unroll
          for (int cb = 0; cb < 2; ++cb)
#pragma unroll
            for (int q = 0; q < 4; ++q)
              Gf[(rb * 16 + l4 * 4 + q) * 129 + wv * 32 + cb * 16 + l15] = acc0[rb][cb][q] + bias0c[cb];
      }
      __syncthreads();  // B3: Gf(L0) ready AND all A(h0) reads done

      // issue h1 batch2 (rows 16..31) — covered by cell0 VALU
      u64 ha2[4], hb2[4];
      if (l1act) {
#pragma unroll
        for (int c = 0; c < 4; ++c) {
          int li = (c + 4) * 256 + tid;
          ha2[c] = ld_coh8(h1s64 + li * 2); hb2[c] = ld_coh8(h1s64 + li * 2 + 1);
        }
      }
      if (l0act) {
        // ---- cell0: gates + W_ih0 gather + c/h update, 8B coherent store ----
        float g4[4][4];
#pragma unroll
        for (int g = 0; g < 4; ++g)
#pragma unroll
          for (int j = 0; j < 4; ++j) g4[g][j] = Gf[rC * 129 + g * 32 + u0C + j];
        if (tau >= 1) {
          int zr = z[(row0 + rC) * TT + (tau - 1)];
          const u16* gb = wl0b + (size_t)zr * 2048 + w * 32 + u0C;
#pragma unroll
          for (int g = 0; g < 4; ++g) {
            u64 v = *(const u64*)(gb + g * 512);
#pragma unroll
            for (int j = 0; j < 4; ++j) g4[g][j] += b2f((u16)(v >> (16 * j)));
          }
        }
        u64 pk = 0;
#pragma unroll
        for (int j = 0; j < 4; ++j) {
          float cn = sigf(g4[1][j]) * c0s[j] + sigf(g4[0][j]) * tanh_f(g4[2][j]);
          float hn = sigf(g4[3][j]) * tanh_f(cn);
          c0s[j] = cn;
          pk |= ((u64)f2b(hn)) << (16 * j);
        }
        u16* h0w = h0buf + (tau & 1) * HB + row0 * 512;
        st_coh8((u64*)(h0w + rC * 512 + w * 32 + u0C), pk);
      }
      if (l1act) {
        // overwrite A with h1(tau-2)
#pragma unroll
        for (int c = 0; c < 4; ++c) {
          int li = c * 256 + tid, row = li >> 6, cc = li & 63;
          u64* d = (u64*)(A + row * A_ST + cc * 8);
          d[0] = ha[c]; d[1] = hb[c];
        }
#pragma unroll
        for (int c = 0; c < 4; ++c) {
          int li = (c + 4) * 256 + tid, row = li >> 6, cc = li & 63;
          u64* d = (u64*)(A + row * A_ST + cc * 8);
          d[0] = ha2[c]; d[1] = hb2[c];
        }
      }
      __syncthreads();  // B4: A(h1) ready AND cell0 Gf reads done

      if (l1act) {
#pragma unroll
        for (int kb = 16; kb < 32; ++kb) {
          bf16x8 a0 = ldA(0, kb - 16), a1 = ldA(1, kb - 16);
#pragma unroll
          for (int cb = 0; cb < 2; ++cb) {
            acc1[0][cb] = __builtin_amdgcn_mfma_f32_16x16x32_bf16(a0, bq1R[cb * 32 + kb], acc1[0][cb], 0, 0, 0);
            acc1[1][cb] = __builtin_amdgcn_mfma_f32_16x16x32_bf16(a1, bq1R[cb * 32 + kb], acc1[1][cb], 0, 0, 0);
          }
        }
#pragma unroll
        for (int rb = 0; rb < 2; ++rb)
#pragma unroll
          for (int cb = 0; cb < 2; ++cb)
#pragma unroll
            for (int q = 0; q < 4; ++q)
              Gf[(rb * 16 + l4 * 4 + q) * 129 + wv * 32 + cb * 16 + l15] = acc1[rb][cb][q] + bias1c[cb];
      }
      __syncthreads();  // B5: Gf(L1) ready

      if (l1act) {
        float g4[4][4];
#pragma unroll
        for (int g = 0; g < 4; ++g)
#pragma unroll
          for (int j = 0; j < 4; ++j) g4[g][j] = Gf[rC * 129 + g * 32 + u0C + j];
        u64 pk = 0;
#pragma unroll
        for (int j = 0; j < 4; ++j) {
          float cn = sigf(g4[1][j]) * c1s[j] + sigf(g4[0][j]) * tanh_f(g4[2][j]);
          float hn = sigf(g4[3][j]) * tanh_f(cn);
          c1s[j] = cn;
          pk |= ((u64)f2b(hn)) << (16 * j);
        }
        u16* h1w = h1buf + ((tau + 1) & 1) * HB + row0 * 512;
        st_coh8((u64*)(h1w + rC * 512 + w * 32 + u0C), pk);
      }
      __syncthreads();  // B6: per-wave vmcnt(0) drain => all coherent stores visible
      if (tid == 0) fadd(F);
    } else {
      // ---------------- logits WG: NLL(tau-2) ----------------
      const bool lgact = (tau >= 2);
      if (lgact) {
        u64 ta[8], tb[8];
#pragma unroll
        for (int c = 0; c < 8; ++c) {
          int li = c * 256 + tid;
          ta[c] = ld_coh8(h1s64 + li * 2); tb[c] = ld_coh8(h1s64 + li * 2 + 1);
        }
#pragma unroll
        for (int c = 0; c < 8; ++c) {
          int li = c * 256 + tid, row = li >> 6, cc = li & 63;
          u64* d = (u64*)(A + row * A_ST + cc * 8);
          d[0] = ta[c]; d[1] = tb[c];
        }
      }
      __syncthreads();  // B2: staged (loads retired)
      if (tid == 0) fadd(F);  // early release: WAR obligation met; rest is local
      if (lgact) {
        f32x4 accL[2][2] = {{VZ, VZ}, {VZ, VZ}};
#pragma unroll
        for (int kb = 0; kb < 16; ++kb) {
          bf16x8 a0 = ldA(0, kb), a1 = ldA(1, kb);
#pragma unroll
          for (int cb = 0; cb < 2; ++cb) {
            accL[0][cb] = __builtin_amdgcn_mfma_f32_16x16x32_bf16(a0, wlR[cb * 16 + kb], accL[0][cb], 0, 0, 0);
            accL[1][cb] = __builtin_amdgcn_mfma_f32_16x16x32_bf16(a1, wlR[cb * 16 + kb], accL[1][cb], 0, 0, 0);
          }
        }
#pragma unroll
        for (int rb = 0; rb < 2; ++rb)
#pragma unroll
          for (int cb = 0; cb < 2; ++cb)
#pragma unroll
            for (int q = 0; q < 4; ++q)
              Gf[(rb * 16 + l4 * 4 + q) * 129 + wv * 32 + cb * 16 + l15] = accL[rb][cb][q] + biasLc[cb];
      }
      __syncthreads();  // B3: Gf ready
      if (lgact) {
        int t2 = tau - 2;
        int r = cuL, k = rgL;            // 8 threads per row x 16 cols
        float vloc[16], mloc = -3.4e38f;
#pragma unroll
        for (int j = 0; j < 16; ++j) {
          vloc[j] = Gf[r * 129 + k * 16 + j];
          mloc = fmaxf(mloc, vloc[j]);
        }
        Pm[r * 8 + k] = mloc;
        __syncthreads();
        float mrow = Pm[r * 8];
#pragma unroll
        for (int j = 1; j < 8; ++j) mrow = fmaxf(mrow, Pm[r * 8 + j]);
        int zr = z[(row0 + r) * TT + t2];
        float sloc = 0.f, tloc = 0.f;
#pragma unroll
        for (int j = 0; j < 16; ++j) {
          sloc += __expf(vloc[j] - mrow);
          tloc += (k * 16 + j == zr) ? vloc[j] : 0.f;
        }
        Ps[r * 8 + k] = sloc; Pt[r * 8 + k] = tloc;
        __syncthreads();
        if (k == 0) {
          float s = 0.f, tv = 0.f;
#pragma unroll
          for (int j = 0; j < 8; ++j) { s += Ps[r * 8 + j]; tv += Pt[r * 8 + j]; }
          if ((float)t2 < nflv) accN += mrow + __logf(s) - tv;
        }
      } else {
        __syncthreads(); __syncthreads();
      }
    }
  }

  if (!isC && rgL == 0) out[row0 + cuL] = accN * (1.0f / TT);
}

extern "C" void kernel_launch(void* const* d_in, const int* in_sizes, int n_in,
                              void* d_out, int out_size, void* d_ws, size_t ws_size,
                              hipStream_t stream) {
  const float* wih0 = (const float*)d_in[0];
  const float* whh0 = (const float*)d_in[1];
  const float* bih0 = (const float*)d_in[2];
  const float* bhh0 = (const float*)d_in[3];
  const float* wih1 = (const float*)d_in[4];
  const float* whh1 = (const float*)d_in[5];
  const float* bih1 = (const float*)d_in[6];
  const float* bhh1 = (const float*)d_in[7];
  const float* wlinf = (const float*)d_in[8];
  const float* blin = (const float*)d_in[9];
  const int* z = (const int*)d_in[10];
  const int* nfr = (const int*)d_in[11];
  float* out = (float*)d_out;
  char* ws = (char*)d_ws;
  u16* wl0a = (u16*)(ws + WL0A_OFF);
  u16* wl0b = (u16*)(ws + WL0B_OFF);
  u16* wl1 = (u16*)(ws + WL1_OFF);
  u16* wlin = (u16*)(ws + WLIN_OFF);
  u16* h0buf = (u16*)(ws + H0_OFF);
  u16* h1buf = (u16*)(ws + H1_OFF);
  u32* bars = (u32*)(ws + BAR_OFF);

  hipMemsetAsync(ws + BAR_OFF, 0, 2048, stream);
  const int NTOT = 2048 * 512 + 128 * 2048 + 2048 * 1024 + 128 * 512;
  prep_kernel<<<dim3((NTOT + 255) / 256), dim3(256), 0, stream>>>(
      wih0, whh0, wih1, whh1, wlinf, wl0a, wl0b, wl1, wlin);
  lstm_kernel<<<dim3(NWG), dim3(256), LDS_BYTES, stream>>>(
      bih0, bhh0, bih1, bhh1, blin, z, nfr, wl0a, wl0b, wl1, wlin, h0buf, h1buf, bars, out);
}